// Round 4
// baseline (212.208 us; speedup 1.0000x reference)
//
#include <hip/hip_runtime.h>

constexpr int H = 4;
constexpr int F = 16;
constexpr int NODE_F = 128;
constexpr int EDGE_F = 64;
constexpr float NEG_SLOPE = 0.2f;

// ---------------- fold: Wl/Wr [128x4], We [64x4], bv[12]; zero the global counter ----
__global__ void fold_kernel(const float* __restrict__ Wn, const float* __restrict__ bn,
                            const float* __restrict__ Wed, const float* __restrict__ bed,
                            const float* __restrict__ al, const float* __restrict__ ar,
                            const float* __restrict__ ae,
                            float* __restrict__ Wl, float* __restrict__ Wr,
                            float* __restrict__ We, float* __restrict__ bv,
                            int* __restrict__ total) {
    int idx = threadIdx.x;  // 512 threads, 1 block
    if (idx == 0) *total = 0;
    if (idx < NODE_F * H) {
        int k = idx >> 2, h = idx & 3;
        float sl = 0.f, sr = 0.f;
        #pragma unroll
        for (int f = 0; f < F; ++f) {
            float w = Wn[k * (H * F) + h * F + f];
            sl += w * al[h * F + f];
            sr += w * ar[h * F + f];
        }
        Wl[idx] = sl; Wr[idx] = sr;
    }
    if (idx < EDGE_F * H) {
        int k = idx >> 2, h = idx & 3;
        float s = 0.f;
        #pragma unroll
        for (int f = 0; f < F; ++f) s += Wed[k * (H * F) + h * F + f] * ae[h * F + f];
        We[idx] = s;
    }
    if (idx < H) {
        float sl = 0.f, sr = 0.f, se = 0.f;
        #pragma unroll
        for (int f = 0; f < F; ++f) {
            sl += bn[idx * F + f] * al[idx * F + f];
            sr += bn[idx * F + f] * ar[idx * F + f];
            se += bed[idx * F + f] * ae[idx * F + f];
        }
        bv[idx] = sl; bv[H + idx] = sr; bv[2 * H + idx] = se;
    }
}

// ---------------- node proj: 4 lanes per node, coalesced 64B-line reads ----
__global__ void node_proj_kernel(const float* __restrict__ nfeat,
                                 const float* __restrict__ Wl, const float* __restrict__ Wr,
                                 const float* __restrict__ bv,
                                 float* __restrict__ el, float* __restrict__ er,
                                 int* __restrict__ deg, int N) {
    __shared__ float sWl[NODE_F * H];
    __shared__ float sWr[NODE_F * H];
    for (int i = threadIdx.x; i < NODE_F * H; i += blockDim.x) { sWl[i] = Wl[i]; sWr[i] = Wr[i]; }
    __syncthreads();
    int lane = threadIdx.x & 63;
    int wave = (int)(((size_t)blockIdx.x * blockDim.x + threadIdx.x) >> 6);
    int sub = lane & 3, ln = lane >> 2;
    int n = wave * 16 + ln;
    if (n >= N) return;
    float accl[H] = {0.f, 0.f, 0.f, 0.f};
    float accr[H] = {0.f, 0.f, 0.f, 0.f};
    const float4* row = (const float4*)(nfeat + (size_t)n * NODE_F);
    #pragma unroll
    for (int i = 0; i < 8; ++i) {
        float4 v = row[sub + 4 * i];
        int k0 = (sub + 4 * i) * 4;
        #pragma unroll
        for (int h = 0; h < H; ++h) {
            accl[h] += v.x * sWl[(k0 + 0) * H + h] + v.y * sWl[(k0 + 1) * H + h]
                     + v.z * sWl[(k0 + 2) * H + h] + v.w * sWl[(k0 + 3) * H + h];
            accr[h] += v.x * sWr[(k0 + 0) * H + h] + v.y * sWr[(k0 + 1) * H + h]
                     + v.z * sWr[(k0 + 2) * H + h] + v.w * sWr[(k0 + 3) * H + h];
        }
    }
    #pragma unroll
    for (int m = 1; m < 4; m <<= 1) {
        #pragma unroll
        for (int h = 0; h < H; ++h) {
            accl[h] += __shfl_xor(accl[h], m);
            accr[h] += __shfl_xor(accr[h], m);
        }
    }
    el[(size_t)n * H + sub] = accl[sub] + bv[sub];
    er[(size_t)n * H + sub] = accr[sub] + bv[H + sub];
    if (sub == 0) deg[n] = 0;
}

// ---------------- hist: idx[e] = slot within dst segment ----
__global__ void hist_kernel(const int* __restrict__ dst, int* __restrict__ deg,
                            int* __restrict__ idx, int E) {
    int e = blockIdx.x * blockDim.x + threadIdx.x;
    if (e >= E) return;
    idx[e] = atomicAdd(deg + dst[e], 1);
}

// ---------------- offsets: wave-scan + one atomic per wave (segment base order is
// run-varying but per-node contents identical — same class as hist atomics) ----
__global__ void offsets_kernel(const int* __restrict__ deg, int* __restrict__ off,
                               int* __restrict__ total, int N) {
    int lane = threadIdx.x & 63;
    int gid = blockIdx.x * blockDim.x + threadIdx.x;
    int x = (gid < N) ? deg[gid] : 0;
    int incl = x;
    #pragma unroll
    for (int s = 1; s < 64; s <<= 1) {
        int y = __shfl_up(incl, s);
        if (lane >= s) incl += y;
    }
    int wtot = __shfl(incl, 63);
    int base = 0;
    if (lane == 63) base = atomicAdd(total, wtot);
    base = __shfl(base, 63);
    if (gid < N) off[gid] = base + incl - x;
}

// ---------------- edge proj: 4 lanes/edge, coalesced efeat stream; payload scattered
// DIRECTLY into CSR slot (16B per edge, 4-lane-contiguous) — no eid indirection ----
__global__ void edge_proj_kernel(const float* __restrict__ efeat,
                                 const int* __restrict__ src, const int* __restrict__ dst,
                                 const float* __restrict__ We, const float* __restrict__ bv,
                                 const float* __restrict__ el,
                                 const int* __restrict__ off, const int* __restrict__ idx,
                                 float* __restrict__ payload, int E) {
    __shared__ float sWe[EDGE_F * H];
    __shared__ float sbe[H];
    for (int i = threadIdx.x; i < EDGE_F * H; i += blockDim.x) sWe[i] = We[i];
    if (threadIdx.x < H) sbe[threadIdx.x] = bv[2 * H + threadIdx.x];
    __syncthreads();
    int lane = threadIdx.x & 63;
    int wave = (int)(((size_t)blockIdx.x * blockDim.x + threadIdx.x) >> 6);
    int sub = lane & 3, le = lane >> 2;
    int e = wave * 16 + le;
    if (e >= E) return;
    float acc[H] = {0.f, 0.f, 0.f, 0.f};
    const float4* row = (const float4*)(efeat + (size_t)e * EDGE_F);
    #pragma unroll
    for (int i = 0; i < 4; ++i) {
        float4 v = row[sub + 4 * i];
        int k0 = (sub + 4 * i) * 4;
        #pragma unroll
        for (int h = 0; h < H; ++h) {
            acc[h] += v.x * sWe[(k0 + 0) * H + h] + v.y * sWe[(k0 + 1) * H + h]
                    + v.z * sWe[(k0 + 2) * H + h] + v.w * sWe[(k0 + 3) * H + h];
        }
    }
    #pragma unroll
    for (int m = 1; m < 4; m <<= 1) {
        #pragma unroll
        for (int h = 0; h < H; ++h) acc[h] += __shfl_xor(acc[h], m);
    }
    int s = src[e];
    int pos = off[dst[e]] + idx[e];
    payload[(size_t)pos * H + sub] = el[(size_t)s * H + sub] + acc[sub] + sbe[sub];
}

// ---------------- node reduce: 16 lanes/node, CONTIGUOUS payload segment, streaming ----
__global__ void node_reduce_kernel(const float* __restrict__ payload,
                                   const int* __restrict__ off, const int* __restrict__ deg,
                                   const float* __restrict__ er,
                                   float* __restrict__ out, int N) {
    int lane = threadIdx.x & 63;
    int wave = (int)(((size_t)blockIdx.x * blockDim.x + threadIdx.x) >> 6);
    int g = lane >> 4;            // group 0..3 within wave
    int gl = lane & 15;           // lane within group
    int n = wave * 4 + g;
    if (n >= N) return;
    int o = off[n], dg = deg[n];
    float4 erv = *(const float4*)(er + (size_t)n * H);
    float n0 = 0.f, n1 = 0.f, n2 = 0.f, n3 = 0.f;
    float d0 = 0.f, d1 = 0.f, d2 = 0.f, d3 = 0.f;
    for (int i = gl; i < dg; i += 16) {
        float4 p = *(const float4*)(payload + (size_t)(o + i) * H);
        float e0 = p.x + erv.x, e1 = p.y + erv.y, e2 = p.z + erv.z, e3 = p.w + erv.w;
        e0 = e0 > 0.f ? e0 : NEG_SLOPE * e0;
        e1 = e1 > 0.f ? e1 : NEG_SLOPE * e1;
        e2 = e2 > 0.f ? e2 : NEG_SLOPE * e2;
        e3 = e3 > 0.f ? e3 : NEG_SLOPE * e3;
        float x0 = expf(e0), x1 = expf(e1), x2 = expf(e2), x3 = expf(e3);
        n0 += x0 * p.x; n1 += x1 * p.y; n2 += x2 * p.z; n3 += x3 * p.w;
        d0 += x0; d1 += x1; d2 += x2; d3 += x3;
    }
    #pragma unroll
    for (int s = 8; s; s >>= 1) {
        n0 += __shfl_down(n0, s, 16); n1 += __shfl_down(n1, s, 16);
        n2 += __shfl_down(n2, s, 16); n3 += __shfl_down(n3, s, 16);
        d0 += __shfl_down(d0, s, 16); d1 += __shfl_down(d1, s, 16);
        d2 += __shfl_down(d2, s, 16); d3 += __shfl_down(d3, s, 16);
    }
    if (gl == 0) {
        *(float4*)(out + (size_t)n * H) =
            make_float4(d0 > 0.f ? n0 / d0 : 0.f, d1 > 0.f ? n1 / d1 : 0.f,
                        d2 > 0.f ? n2 / d2 : 0.f, d3 > 0.f ? n3 / d3 : 0.f);
    }
}

// ---------------- fallback (small ws): fused atomic path ----
__global__ void zero_kernel(float* __restrict__ p, int n) {
    int i = blockIdx.x * blockDim.x + threadIdx.x;
    if (i < n) p[i] = 0.f;
}

__global__ void edge_atomic_kernel(const float* __restrict__ efeat,
                                   const int* __restrict__ src, const int* __restrict__ dst,
                                   const float* __restrict__ We, const float* __restrict__ bv,
                                   const float* __restrict__ el, const float* __restrict__ er,
                                   float* __restrict__ num, float* __restrict__ den, int E) {
    __shared__ float sWe[EDGE_F * H];
    __shared__ float sbe[H];
    for (int i = threadIdx.x; i < EDGE_F * H; i += blockDim.x) sWe[i] = We[i];
    if (threadIdx.x < H) sbe[threadIdx.x] = bv[2 * H + threadIdx.x];
    __syncthreads();
    int e = blockIdx.x * blockDim.x + threadIdx.x;
    if (e >= E) return;
    float acc[H] = {sbe[0], sbe[1], sbe[2], sbe[3]};
    const float4* row = (const float4*)(efeat + (size_t)e * EDGE_F);
    #pragma unroll
    for (int j = 0; j < EDGE_F / 4; ++j) {
        float4 v = row[j];
        #pragma unroll
        for (int h = 0; h < H; ++h) {
            acc[h] += v.x * sWe[(4 * j + 0) * H + h] + v.y * sWe[(4 * j + 1) * H + h]
                    + v.z * sWe[(4 * j + 2) * H + h] + v.w * sWe[(4 * j + 3) * H + h];
        }
    }
    int s = src[e], d = dst[e];
    float4 elv = *(const float4*)(el + (size_t)s * H);
    float4 erv = *(const float4*)(er + (size_t)d * H);
    float p0 = elv.x + acc[0], p1 = elv.y + acc[1], p2 = elv.z + acc[2], p3 = elv.w + acc[3];
    float e0 = p0 + erv.x, e1 = p1 + erv.y, e2 = p2 + erv.z, e3 = p3 + erv.w;
    e0 = e0 > 0.f ? e0 : NEG_SLOPE * e0;
    e1 = e1 > 0.f ? e1 : NEG_SLOPE * e1;
    e2 = e2 > 0.f ? e2 : NEG_SLOPE * e2;
    e3 = e3 > 0.f ? e3 : NEG_SLOPE * e3;
    float x0 = expf(e0), x1 = expf(e1), x2 = expf(e2), x3 = expf(e3);
    float* nb = num + (size_t)d * H;
    float* db = den + (size_t)d * H;
    atomicAdd(nb + 0, x0 * p0); atomicAdd(nb + 1, x1 * p1);
    atomicAdd(nb + 2, x2 * p2); atomicAdd(nb + 3, x3 * p3);
    atomicAdd(db + 0, x0); atomicAdd(db + 1, x1);
    atomicAdd(db + 2, x2); atomicAdd(db + 3, x3);
}

__global__ void finalize_kernel(const float* __restrict__ num, const float* __restrict__ den,
                                float* __restrict__ out, int NH) {
    int i = blockIdx.x * blockDim.x + threadIdx.x;
    if (i < NH) {
        float d = den[i];
        out[i] = d > 0.f ? num[i] / d : 0.f;
    }
}

extern "C" void kernel_launch(void* const* d_in, const int* in_sizes, int n_in,
                              void* d_out, int out_size, void* d_ws, size_t ws_size,
                              hipStream_t stream) {
    const float* nfeat = (const float*)d_in[0];
    const float* efeat = (const float*)d_in[1];
    const float* Wn    = (const float*)d_in[2];
    const float* bn    = (const float*)d_in[3];
    const float* Wed   = (const float*)d_in[4];
    const float* bed   = (const float*)d_in[5];
    const float* al    = (const float*)d_in[6];
    const float* ar    = (const float*)d_in[7];
    const float* ae    = (const float*)d_in[8];
    const int*   src   = (const int*)d_in[9];
    const int*   dst   = (const int*)d_in[10];

    int N = in_sizes[0] / NODE_F;
    int E = in_sizes[1] / EDGE_F;
    float* out = (float*)d_out;
    float* ws  = (float*)d_ws;

    // CSR layout (float-element offsets; all 16B aligned)
    size_t p_payload = 0;                    // E*4 floats, CSR order
    size_t p_el   = p_payload + (size_t)E * 4;
    size_t p_er   = p_el + (size_t)N * H;
    size_t p_Wl   = p_er + (size_t)N * H;
    size_t p_Wr   = p_Wl + 512;
    size_t p_We   = p_Wr + 512;
    size_t p_bv   = p_We + 256;
    size_t p_tot  = p_bv + 16;               // 1 int (+pad)
    size_t p_deg  = p_tot + 16;              // N ints
    size_t p_off  = p_deg + (size_t)N;       // N ints
    size_t p_idx  = p_off + (size_t)N;       // E ints
    size_t csr_total = (p_idx + (size_t)E) * sizeof(float);

    if (ws_size >= csr_total) {
        float* payload = ws + p_payload;
        float* el = ws + p_el;
        float* er = ws + p_er;
        float* Wl = ws + p_Wl;
        float* Wr = ws + p_Wr;
        float* We = ws + p_We;
        float* bv = ws + p_bv;
        int* total = (int*)(ws + p_tot);
        int* deg = (int*)(ws + p_deg);
        int* off = (int*)(ws + p_off);
        int* idx = (int*)(ws + p_idx);

        fold_kernel<<<1, 512, 0, stream>>>(Wn, bn, Wed, bed, al, ar, ae, Wl, Wr, We, bv, total);
        node_proj_kernel<<<(int)(((size_t)N * 4 + 255) / 256), 256, 0, stream>>>(
            nfeat, Wl, Wr, bv, el, er, deg, N);
        hist_kernel<<<(E + 255) / 256, 256, 0, stream>>>(dst, deg, idx, E);
        offsets_kernel<<<(N + 255) / 256, 256, 0, stream>>>(deg, off, total, N);
        edge_proj_kernel<<<(int)(((size_t)E * 4 + 255) / 256), 256, 0, stream>>>(
            efeat, src, dst, We, bv, el, off, idx, payload, E);
        node_reduce_kernel<<<(int)(((size_t)N * 16 + 255) / 256), 256, 0, stream>>>(
            payload, off, deg, er, out, N);
    } else {
        // atomic fallback layout
        float* el  = ws;
        float* er  = el + (size_t)N * H;
        float* num = er + (size_t)N * H;
        float* den = num + (size_t)N * H;
        float* Wl  = den + (size_t)N * H;
        float* Wr  = Wl + 512;
        float* We  = Wr + 512;
        float* bv  = We + 256;
        int* total = (int*)(bv + 16);
        int* deg   = total + 16;

        fold_kernel<<<1, 512, 0, stream>>>(Wn, bn, Wed, bed, al, ar, ae, Wl, Wr, We, bv, total);
        node_proj_kernel<<<(int)(((size_t)N * 4 + 255) / 256), 256, 0, stream>>>(
            nfeat, Wl, Wr, bv, el, er, deg, N);
        zero_kernel<<<(int)(((size_t)N * 2 * H + 255) / 256), 256, 0, stream>>>(num, N * 2 * H);
        edge_atomic_kernel<<<(E + 255) / 256, 256, 0, stream>>>(efeat, src, dst, We, bv,
                                                                el, er, num, den, E);
        finalize_kernel<<<(N * H + 255) / 256, 256, 0, stream>>>(num, den, out, N * H);
    }
}

// Round 5
// 196.580 us; speedup vs baseline: 1.0795x; 1.0795x over previous
//
#include <hip/hip_runtime.h>
#include <hip/hip_fp16.h>

constexpr int H = 4;
constexpr int F = 16;
constexpr int NODE_F = 128;
constexpr int EDGE_F = 64;
constexpr float NEG_SLOPE = 0.2f;

// ---------------- node proj (fold merged): 4 lanes/node, coalesced 64B-line reads.
// Every block folds Wl/Wr+biases in LDS from Wn/attn (32KB L2-broadcast read).
// Block 0 additionally publishes We/be (for edge_proj) and zeroes `total`.
__global__ void node_proj_kernel(const float* __restrict__ nfeat,
                                 const float* __restrict__ Wn, const float* __restrict__ bn,
                                 const float* __restrict__ Wed, const float* __restrict__ bed,
                                 const float* __restrict__ al, const float* __restrict__ ar,
                                 const float* __restrict__ ae,
                                 float* __restrict__ el, float* __restrict__ er,
                                 float* __restrict__ Weg, float* __restrict__ beg,
                                 int* __restrict__ total, int* __restrict__ deg, int N) {
    __shared__ float sWl[NODE_F * H];
    __shared__ float sWr[NODE_F * H];
    __shared__ float sbl[H];
    __shared__ float sbr[H];
    for (int i = threadIdx.x; i < NODE_F * H; i += blockDim.x) {
        int k = i >> 2, h = i & 3;
        float sl = 0.f, sr = 0.f;
        #pragma unroll
        for (int f = 0; f < F; ++f) {
            float w = Wn[k * (H * F) + h * F + f];
            sl += w * al[h * F + f];
            sr += w * ar[h * F + f];
        }
        sWl[i] = sl; sWr[i] = sr;
    }
    if (threadIdx.x < H) {
        int h = threadIdx.x;
        float bl = 0.f, br = 0.f;
        #pragma unroll
        for (int f = 0; f < F; ++f) {
            bl += bn[h * F + f] * al[h * F + f];
            br += bn[h * F + f] * ar[h * F + f];
        }
        sbl[h] = bl; sbr[h] = br;
    }
    if (blockIdx.x == 0) {
        for (int i = threadIdx.x; i < EDGE_F * H; i += blockDim.x) {
            int k = i >> 2, h = i & 3;
            float s = 0.f;
            #pragma unroll
            for (int f = 0; f < F; ++f) s += Wed[k * (H * F) + h * F + f] * ae[h * F + f];
            Weg[i] = s;
        }
        if (threadIdx.x < H) {
            int h = threadIdx.x;
            float se = 0.f;
            #pragma unroll
            for (int f = 0; f < F; ++f) se += bed[h * F + f] * ae[h * F + f];
            beg[h] = se;
        }
        if (threadIdx.x == 0) *total = 0;
    }
    __syncthreads();
    int lane = threadIdx.x & 63;
    int wave = (int)(((size_t)blockIdx.x * blockDim.x + threadIdx.x) >> 6);
    int sub = lane & 3, ln = lane >> 2;
    int n = wave * 16 + ln;
    if (n >= N) return;
    float accl[H] = {0.f, 0.f, 0.f, 0.f};
    float accr[H] = {0.f, 0.f, 0.f, 0.f};
    const float4* row = (const float4*)(nfeat + (size_t)n * NODE_F);
    #pragma unroll
    for (int i = 0; i < 8; ++i) {
        float4 v = row[sub + 4 * i];
        int k0 = (sub + 4 * i) * 4;
        #pragma unroll
        for (int h = 0; h < H; ++h) {
            accl[h] += v.x * sWl[(k0 + 0) * H + h] + v.y * sWl[(k0 + 1) * H + h]
                     + v.z * sWl[(k0 + 2) * H + h] + v.w * sWl[(k0 + 3) * H + h];
            accr[h] += v.x * sWr[(k0 + 0) * H + h] + v.y * sWr[(k0 + 1) * H + h]
                     + v.z * sWr[(k0 + 2) * H + h] + v.w * sWr[(k0 + 3) * H + h];
        }
    }
    #pragma unroll
    for (int m = 1; m < 4; m <<= 1) {
        #pragma unroll
        for (int h = 0; h < H; ++h) {
            accl[h] += __shfl_xor(accl[h], m);
            accr[h] += __shfl_xor(accr[h], m);
        }
    }
    el[(size_t)n * H + sub] = accl[sub] + sbl[sub];
    er[(size_t)n * H + sub] = accr[sub] + sbr[sub];
    if (sub == 0) deg[n] = 0;
}

// ---------------- edge proj + fused hist: 4 lanes/edge; payload = half4 in EDGE order ----
__global__ void edge_proj_kernel(const float* __restrict__ efeat,
                                 const int* __restrict__ src, const int* __restrict__ dst,
                                 const float* __restrict__ Weg, const float* __restrict__ beg,
                                 const float* __restrict__ el,
                                 uint2* __restrict__ pay, int* __restrict__ idx,
                                 int* __restrict__ deg, int E) {
    __shared__ float sWe[EDGE_F * H];
    __shared__ float sbe[H];
    for (int i = threadIdx.x; i < EDGE_F * H; i += blockDim.x) sWe[i] = Weg[i];
    if (threadIdx.x < H) sbe[threadIdx.x] = beg[threadIdx.x];
    __syncthreads();
    int lane = threadIdx.x & 63;
    int wave = (int)(((size_t)blockIdx.x * blockDim.x + threadIdx.x) >> 6);
    int sub = lane & 3, le = lane >> 2;
    int e = wave * 16 + le;
    if (e >= E) return;
    float acc[H] = {0.f, 0.f, 0.f, 0.f};
    const float4* row = (const float4*)(efeat + (size_t)e * EDGE_F);
    #pragma unroll
    for (int i = 0; i < 4; ++i) {
        float4 v = row[sub + 4 * i];
        int k0 = (sub + 4 * i) * 4;
        #pragma unroll
        for (int h = 0; h < H; ++h) {
            acc[h] += v.x * sWe[(k0 + 0) * H + h] + v.y * sWe[(k0 + 1) * H + h]
                    + v.z * sWe[(k0 + 2) * H + h] + v.w * sWe[(k0 + 3) * H + h];
        }
    }
    #pragma unroll
    for (int m = 1; m < 4; m <<= 1) {
        #pragma unroll
        for (int h = 0; h < H; ++h) acc[h] += __shfl_xor(acc[h], m);
    }
    // after the quad reduce every lane holds all 4 acc values; lane sub==0 finishes the edge
    if (sub == 0) {
        int s = src[e];
        float4 elv = *(const float4*)(el + (size_t)s * H);
        float p0 = elv.x + acc[0] + sbe[0];
        float p1 = elv.y + acc[1] + sbe[1];
        float p2 = elv.z + acc[2] + sbe[2];
        float p3 = elv.w + acc[3] + sbe[3];
        __half2 a = __floats2half2_rn(p0, p1);
        __half2 b = __floats2half2_rn(p2, p3);
        uint2 w;
        w.x = *(unsigned int*)&a;
        w.y = *(unsigned int*)&b;
        pay[e] = w;
        idx[e] = atomicAdd(deg + dst[e], 1);
    }
}

// ---------------- offsets: wave-scan + one atomic per wave (segment base order is
// run-varying but per-node contents identical — same class as hist atomics) ----
__global__ void offsets_kernel(const int* __restrict__ deg, int* __restrict__ off,
                               int* __restrict__ total, int N) {
    int lane = threadIdx.x & 63;
    int gid = blockIdx.x * blockDim.x + threadIdx.x;
    int x = (gid < N) ? deg[gid] : 0;
    int incl = x;
    #pragma unroll
    for (int s = 1; s < 64; s <<= 1) {
        int y = __shfl_up(incl, s);
        if (lane >= s) incl += y;
    }
    int wtot = __shfl(incl, 63);
    int base = 0;
    if (lane == 63) base = atomicAdd(total, wtot);
    base = __shfl(base, 63);
    if (gid < N) off[gid] = base + incl - x;
}

// ---------------- scatter edge ids into CSR slots (4B random writes, nt → MALL) ----
__global__ void scatter_eid_kernel(const int* __restrict__ dst, const int* __restrict__ idx,
                                   const int* __restrict__ off, int* __restrict__ eid, int E) {
    int e = blockIdx.x * blockDim.x + threadIdx.x;
    if (e >= E) return;
    __builtin_nontemporal_store(e, &eid[off[dst[e]] + idx[e]]);
}

// ---------------- node reduce: 16 lanes/node, gather half4 payload via eid ----
__global__ void node_reduce_kernel(const uint2* __restrict__ pay,
                                   const int* __restrict__ eid,
                                   const int* __restrict__ off, const int* __restrict__ deg,
                                   const float* __restrict__ er,
                                   float* __restrict__ out, int N) {
    int lane = threadIdx.x & 63;
    int wave = (int)(((size_t)blockIdx.x * blockDim.x + threadIdx.x) >> 6);
    int g = lane >> 4;            // group 0..3 within wave
    int gl = lane & 15;           // lane within group
    int n = wave * 4 + g;
    if (n >= N) return;
    int o = off[n], dg = deg[n];
    float4 erv = *(const float4*)(er + (size_t)n * H);
    float n0 = 0.f, n1 = 0.f, n2 = 0.f, n3 = 0.f;
    float d0 = 0.f, d1 = 0.f, d2 = 0.f, d3 = 0.f;
    for (int i = gl; i < dg; i += 16) {
        uint2 w = pay[eid[o + i]];
        float2 f01 = __half22float2(*(const __half2*)&w.x);
        float2 f23 = __half22float2(*(const __half2*)&w.y);
        float e0 = f01.x + erv.x, e1 = f01.y + erv.y, e2 = f23.x + erv.z, e3 = f23.y + erv.w;
        e0 = e0 > 0.f ? e0 : NEG_SLOPE * e0;
        e1 = e1 > 0.f ? e1 : NEG_SLOPE * e1;
        e2 = e2 > 0.f ? e2 : NEG_SLOPE * e2;
        e3 = e3 > 0.f ? e3 : NEG_SLOPE * e3;
        float x0 = expf(e0), x1 = expf(e1), x2 = expf(e2), x3 = expf(e3);
        n0 += x0 * f01.x; n1 += x1 * f01.y; n2 += x2 * f23.x; n3 += x3 * f23.y;
        d0 += x0; d1 += x1; d2 += x2; d3 += x3;
    }
    #pragma unroll
    for (int s = 8; s; s >>= 1) {
        n0 += __shfl_down(n0, s, 16); n1 += __shfl_down(n1, s, 16);
        n2 += __shfl_down(n2, s, 16); n3 += __shfl_down(n3, s, 16);
        d0 += __shfl_down(d0, s, 16); d1 += __shfl_down(d1, s, 16);
        d2 += __shfl_down(d2, s, 16); d3 += __shfl_down(d3, s, 16);
    }
    if (gl == 0) {
        *(float4*)(out + (size_t)n * H) =
            make_float4(d0 > 0.f ? n0 / d0 : 0.f, d1 > 0.f ? n1 / d1 : 0.f,
                        d2 > 0.f ? n2 / d2 : 0.f, d3 > 0.f ? n3 / d3 : 0.f);
    }
}

// ---------------- fallback (small ws): fused atomic path ----
__global__ void fold_kernel(const float* __restrict__ Wn, const float* __restrict__ bn,
                            const float* __restrict__ Wed, const float* __restrict__ bed,
                            const float* __restrict__ al, const float* __restrict__ ar,
                            const float* __restrict__ ae,
                            float* __restrict__ Wl, float* __restrict__ Wr,
                            float* __restrict__ We, float* __restrict__ bv) {
    int idx = threadIdx.x;  // 512 threads, 1 block
    if (idx < NODE_F * H) {
        int k = idx >> 2, h = idx & 3;
        float sl = 0.f, sr = 0.f;
        #pragma unroll
        for (int f = 0; f < F; ++f) {
            float w = Wn[k * (H * F) + h * F + f];
            sl += w * al[h * F + f];
            sr += w * ar[h * F + f];
        }
        Wl[idx] = sl; Wr[idx] = sr;
    }
    if (idx < EDGE_F * H) {
        int k = idx >> 2, h = idx & 3;
        float s = 0.f;
        #pragma unroll
        for (int f = 0; f < F; ++f) s += Wed[k * (H * F) + h * F + f] * ae[h * F + f];
        We[idx] = s;
    }
    if (idx < H) {
        float sl = 0.f, sr = 0.f, se = 0.f;
        #pragma unroll
        for (int f = 0; f < F; ++f) {
            sl += bn[idx * F + f] * al[idx * F + f];
            sr += bn[idx * F + f] * ar[idx * F + f];
            se += bed[idx * F + f] * ae[idx * F + f];
        }
        bv[idx] = sl; bv[H + idx] = sr; bv[2 * H + idx] = se;
    }
}

__global__ void node_proj_fb_kernel(const float* __restrict__ nfeat,
                                    const float* __restrict__ Wl, const float* __restrict__ Wr,
                                    const float* __restrict__ bv,
                                    float* __restrict__ el, float* __restrict__ er,
                                    float* __restrict__ num, float* __restrict__ den, int N) {
    __shared__ float sWl[NODE_F * H];
    __shared__ float sWr[NODE_F * H];
    for (int i = threadIdx.x; i < NODE_F * H; i += blockDim.x) { sWl[i] = Wl[i]; sWr[i] = Wr[i]; }
    __syncthreads();
    int n = blockIdx.x * blockDim.x + threadIdx.x;
    if (n >= N) return;
    float accl[H] = {0.f, 0.f, 0.f, 0.f};
    float accr[H] = {0.f, 0.f, 0.f, 0.f};
    const float4* row = (const float4*)(nfeat + (size_t)n * NODE_F);
    #pragma unroll
    for (int j = 0; j < NODE_F / 4; ++j) {
        float4 v = row[j];
        #pragma unroll
        for (int h = 0; h < H; ++h) {
            accl[h] += v.x * sWl[(4 * j + 0) * H + h] + v.y * sWl[(4 * j + 1) * H + h]
                     + v.z * sWl[(4 * j + 2) * H + h] + v.w * sWl[(4 * j + 3) * H + h];
            accr[h] += v.x * sWr[(4 * j + 0) * H + h] + v.y * sWr[(4 * j + 1) * H + h]
                     + v.z * sWr[(4 * j + 2) * H + h] + v.w * sWr[(4 * j + 3) * H + h];
        }
    }
    size_t base = (size_t)n * H;
    #pragma unroll
    for (int h = 0; h < H; ++h) {
        el[base + h] = accl[h] + bv[h];
        er[base + h] = accr[h] + bv[H + h];
        num[base + h] = 0.f;
        den[base + h] = 0.f;
    }
}

__global__ void edge_atomic_kernel(const float* __restrict__ efeat,
                                   const int* __restrict__ src, const int* __restrict__ dst,
                                   const float* __restrict__ We, const float* __restrict__ bv,
                                   const float* __restrict__ el, const float* __restrict__ er,
                                   float* __restrict__ num, float* __restrict__ den, int E) {
    __shared__ float sWe[EDGE_F * H];
    __shared__ float sbe[H];
    for (int i = threadIdx.x; i < EDGE_F * H; i += blockDim.x) sWe[i] = We[i];
    if (threadIdx.x < H) sbe[threadIdx.x] = bv[2 * H + threadIdx.x];
    __syncthreads();
    int e = blockIdx.x * blockDim.x + threadIdx.x;
    if (e >= E) return;
    float acc[H] = {sbe[0], sbe[1], sbe[2], sbe[3]};
    const float4* row = (const float4*)(efeat + (size_t)e * EDGE_F);
    #pragma unroll
    for (int j = 0; j < EDGE_F / 4; ++j) {
        float4 v = row[j];
        #pragma unroll
        for (int h = 0; h < H; ++h) {
            acc[h] += v.x * sWe[(4 * j + 0) * H + h] + v.y * sWe[(4 * j + 1) * H + h]
                    + v.z * sWe[(4 * j + 2) * H + h] + v.w * sWe[(4 * j + 3) * H + h];
        }
    }
    int s = src[e], d = dst[e];
    float4 elv = *(const float4*)(el + (size_t)s * H);
    float4 erv = *(const float4*)(er + (size_t)d * H);
    float p0 = elv.x + acc[0], p1 = elv.y + acc[1], p2 = elv.z + acc[2], p3 = elv.w + acc[3];
    float e0 = p0 + erv.x, e1 = p1 + erv.y, e2 = p2 + erv.z, e3 = p3 + erv.w;
    e0 = e0 > 0.f ? e0 : NEG_SLOPE * e0;
    e1 = e1 > 0.f ? e1 : NEG_SLOPE * e1;
    e2 = e2 > 0.f ? e2 : NEG_SLOPE * e2;
    e3 = e3 > 0.f ? e3 : NEG_SLOPE * e3;
    float x0 = expf(e0), x1 = expf(e1), x2 = expf(e2), x3 = expf(e3);
    float* nb = num + (size_t)d * H;
    float* db = den + (size_t)d * H;
    atomicAdd(nb + 0, x0 * p0); atomicAdd(nb + 1, x1 * p1);
    atomicAdd(nb + 2, x2 * p2); atomicAdd(nb + 3, x3 * p3);
    atomicAdd(db + 0, x0); atomicAdd(db + 1, x1);
    atomicAdd(db + 2, x2); atomicAdd(db + 3, x3);
}

__global__ void finalize_kernel(const float* __restrict__ num, const float* __restrict__ den,
                                float* __restrict__ out, int NH) {
    int i = blockIdx.x * blockDim.x + threadIdx.x;
    if (i < NH) {
        float d = den[i];
        out[i] = d > 0.f ? num[i] / d : 0.f;
    }
}

extern "C" void kernel_launch(void* const* d_in, const int* in_sizes, int n_in,
                              void* d_out, int out_size, void* d_ws, size_t ws_size,
                              hipStream_t stream) {
    const float* nfeat = (const float*)d_in[0];
    const float* efeat = (const float*)d_in[1];
    const float* Wn    = (const float*)d_in[2];
    const float* bn    = (const float*)d_in[3];
    const float* Wed   = (const float*)d_in[4];
    const float* bed   = (const float*)d_in[5];
    const float* al    = (const float*)d_in[6];
    const float* ar    = (const float*)d_in[7];
    const float* ae    = (const float*)d_in[8];
    const int*   src   = (const int*)d_in[9];
    const int*   dst   = (const int*)d_in[10];

    int N = in_sizes[0] / NODE_F;
    int E = in_sizes[1] / EDGE_F;
    float* out = (float*)d_out;
    float* ws  = (float*)d_ws;

    // CSR layout (float-element offsets; all 16B aligned)
    size_t p_pay  = 0;                       // E uint2 (half4 per edge, edge order)
    size_t p_el   = p_pay + (size_t)E * 2;
    size_t p_er   = p_el + (size_t)N * H;
    size_t p_Weg  = p_er + (size_t)N * H;
    size_t p_beg  = p_Weg + 256;
    size_t p_tot  = p_beg + 16;              // 1 int (+pad)
    size_t p_deg  = p_tot + 16;              // N ints
    size_t p_off  = p_deg + (size_t)N;       // N ints
    size_t p_idx  = p_off + (size_t)N;       // E ints
    size_t p_eid  = p_idx + (size_t)E;       // E ints
    size_t csr_total = (p_eid + (size_t)E) * sizeof(float);

    if (ws_size >= csr_total) {
        uint2* pay = (uint2*)(ws + p_pay);
        float* el  = ws + p_el;
        float* er  = ws + p_er;
        float* Weg = ws + p_Weg;
        float* beg = ws + p_beg;
        int* total = (int*)(ws + p_tot);
        int* deg   = (int*)(ws + p_deg);
        int* off   = (int*)(ws + p_off);
        int* idx   = (int*)(ws + p_idx);
        int* eid   = (int*)(ws + p_eid);

        node_proj_kernel<<<(int)(((size_t)N * 4 + 255) / 256), 256, 0, stream>>>(
            nfeat, Wn, bn, Wed, bed, al, ar, ae, el, er, Weg, beg, total, deg, N);
        edge_proj_kernel<<<(int)(((size_t)E * 4 + 255) / 256), 256, 0, stream>>>(
            efeat, src, dst, Weg, beg, el, pay, idx, deg, E);
        offsets_kernel<<<(N + 255) / 256, 256, 0, stream>>>(deg, off, total, N);
        scatter_eid_kernel<<<(E + 255) / 256, 256, 0, stream>>>(dst, idx, off, eid, E);
        node_reduce_kernel<<<(int)(((size_t)N * 16 + 255) / 256), 256, 0, stream>>>(
            pay, eid, off, deg, er, out, N);
    } else {
        // atomic fallback layout
        float* el  = ws;
        float* er  = el + (size_t)N * H;
        float* num = er + (size_t)N * H;
        float* den = num + (size_t)N * H;
        float* Wl  = den + (size_t)N * H;
        float* Wr  = Wl + 512;
        float* We  = Wr + 512;
        float* bv  = We + 256;

        fold_kernel<<<1, 512, 0, stream>>>(Wn, bn, Wed, bed, al, ar, ae, Wl, Wr, We, bv);
        node_proj_fb_kernel<<<(N + 255) / 256, 256, 0, stream>>>(nfeat, Wl, Wr, bv,
                                                                 el, er, num, den, N);
        edge_atomic_kernel<<<(E + 255) / 256, 256, 0, stream>>>(efeat, src, dst, We, bv,
                                                                el, er, num, den, E);
        finalize_kernel<<<(N * H + 255) / 256, 256, 0, stream>>>(num, den, out, N * H);
    }
}

// Round 6
// 175.038 us; speedup vs baseline: 1.2124x; 1.1231x over previous
//
#include <hip/hip_runtime.h>
#include <hip/hip_fp16.h>

constexpr int H = 4;
constexpr int F = 16;
constexpr int NODE_F = 128;
constexpr int EDGE_F = 64;
constexpr float NEG_SLOPE = 0.2f;

// ---------------- fold: Wl/Wr [128x4], We [64x4], bv[12]; zero the global counter ----
__global__ void fold_kernel(const float* __restrict__ Wn, const float* __restrict__ bn,
                            const float* __restrict__ Wed, const float* __restrict__ bed,
                            const float* __restrict__ al, const float* __restrict__ ar,
                            const float* __restrict__ ae,
                            float* __restrict__ Wl, float* __restrict__ Wr,
                            float* __restrict__ We, float* __restrict__ bv,
                            int* __restrict__ total) {
    int idx = threadIdx.x;  // 512 threads, 1 block
    if (idx == 0) *total = 0;
    if (idx < NODE_F * H) {
        int k = idx >> 2, h = idx & 3;
        float sl = 0.f, sr = 0.f;
        #pragma unroll
        for (int f = 0; f < F; ++f) {
            float w = Wn[k * (H * F) + h * F + f];
            sl += w * al[h * F + f];
            sr += w * ar[h * F + f];
        }
        Wl[idx] = sl; Wr[idx] = sr;
    }
    if (idx < EDGE_F * H) {
        int k = idx >> 2, h = idx & 3;
        float s = 0.f;
        #pragma unroll
        for (int f = 0; f < F; ++f) s += Wed[k * (H * F) + h * F + f] * ae[h * F + f];
        We[idx] = s;
    }
    if (idx < H) {
        float sl = 0.f, sr = 0.f, se = 0.f;
        #pragma unroll
        for (int f = 0; f < F; ++f) {
            sl += bn[idx * F + f] * al[idx * F + f];
            sr += bn[idx * F + f] * ar[idx * F + f];
            se += bed[idx * F + f] * ae[idx * F + f];
        }
        bv[idx] = sl; bv[H + idx] = sr; bv[2 * H + idx] = se;
    }
}

// ---------------- node proj: 4 lanes/node, coalesced 64B-line reads, b128 LDS loads ----
__global__ void node_proj_kernel(const float* __restrict__ nfeat,
                                 const float* __restrict__ Wl, const float* __restrict__ Wr,
                                 const float* __restrict__ bv,
                                 float* __restrict__ el, float* __restrict__ er,
                                 int* __restrict__ deg, int N) {
    __shared__ float sWl[NODE_F * H];
    __shared__ float sWr[NODE_F * H];
    for (int i = threadIdx.x; i < NODE_F * H; i += blockDim.x) { sWl[i] = Wl[i]; sWr[i] = Wr[i]; }
    __syncthreads();
    int lane = threadIdx.x & 63;
    int wave = (int)(((size_t)blockIdx.x * blockDim.x + threadIdx.x) >> 6);
    int sub = lane & 3, ln = lane >> 2;
    int n = wave * 16 + ln;
    if (n >= N) return;
    float accl[H] = {0.f, 0.f, 0.f, 0.f};
    float accr[H] = {0.f, 0.f, 0.f, 0.f};
    const float4* row = (const float4*)(nfeat + (size_t)n * NODE_F);
    #pragma unroll
    for (int i = 0; i < 8; ++i) {
        float4 v = row[sub + 4 * i];
        int k0 = (sub + 4 * i) * 4;
        float vv[4] = {v.x, v.y, v.z, v.w};
        #pragma unroll
        for (int j = 0; j < 4; ++j) {
            float4 wl = *(const float4*)&sWl[(k0 + j) * H];
            float4 wr = *(const float4*)&sWr[(k0 + j) * H];
            accl[0] += vv[j] * wl.x; accl[1] += vv[j] * wl.y;
            accl[2] += vv[j] * wl.z; accl[3] += vv[j] * wl.w;
            accr[0] += vv[j] * wr.x; accr[1] += vv[j] * wr.y;
            accr[2] += vv[j] * wr.z; accr[3] += vv[j] * wr.w;
        }
    }
    #pragma unroll
    for (int m = 1; m < 4; m <<= 1) {
        #pragma unroll
        for (int h = 0; h < H; ++h) {
            accl[h] += __shfl_xor(accl[h], m);
            accr[h] += __shfl_xor(accr[h], m);
        }
    }
    el[(size_t)n * H + sub] = accl[sub] + bv[sub];
    er[(size_t)n * H + sub] = accr[sub] + bv[H + sub];
    if (sub == 0) deg[n] = 0;
}

// ---------------- edge proj + fused hist: 4 lanes/edge; half4 payload in EDGE order ----
__global__ void edge_proj_kernel(const float* __restrict__ efeat,
                                 const int* __restrict__ src, const int* __restrict__ dst,
                                 const float* __restrict__ We, const float* __restrict__ bv,
                                 const float* __restrict__ el,
                                 uint2* __restrict__ pay, unsigned short* __restrict__ idx,
                                 int* __restrict__ deg, int E) {
    __shared__ float sWe[EDGE_F * H];
    __shared__ float sbe[H];
    for (int i = threadIdx.x; i < EDGE_F * H; i += blockDim.x) sWe[i] = We[i];
    if (threadIdx.x < H) sbe[threadIdx.x] = bv[2 * H + threadIdx.x];
    __syncthreads();
    int lane = threadIdx.x & 63;
    int wave = (int)(((size_t)blockIdx.x * blockDim.x + threadIdx.x) >> 6);
    int sub = lane & 3, le = lane >> 2;
    int e = wave * 16 + le;
    if (e >= E) return;
    float acc[H] = {0.f, 0.f, 0.f, 0.f};
    const float4* row = (const float4*)(efeat + (size_t)e * EDGE_F);
    #pragma unroll
    for (int i = 0; i < 4; ++i) {
        float4 v = row[sub + 4 * i];
        int k0 = (sub + 4 * i) * 4;
        float vv[4] = {v.x, v.y, v.z, v.w};
        #pragma unroll
        for (int j = 0; j < 4; ++j) {
            float4 w = *(const float4*)&sWe[(k0 + j) * H];
            acc[0] += vv[j] * w.x; acc[1] += vv[j] * w.y;
            acc[2] += vv[j] * w.z; acc[3] += vv[j] * w.w;
        }
    }
    #pragma unroll
    for (int m = 1; m < 4; m <<= 1) {
        #pragma unroll
        for (int h = 0; h < H; ++h) acc[h] += __shfl_xor(acc[h], m);
    }
    if (sub == 0) {
        int s = src[e];
        float4 elv = *(const float4*)(el + (size_t)s * H);
        float p0 = elv.x + acc[0] + sbe[0];
        float p1 = elv.y + acc[1] + sbe[1];
        float p2 = elv.z + acc[2] + sbe[2];
        float p3 = elv.w + acc[3] + sbe[3];
        __half2 a = __floats2half2_rn(p0, p1);
        __half2 b = __floats2half2_rn(p2, p3);
        uint2 w;
        w.x = *(unsigned int*)&a;
        w.y = *(unsigned int*)&b;
        pay[e] = w;
        idx[e] = (unsigned short)atomicAdd(deg + dst[e], 1);
    }
}

// ---------------- offsets: wave-scan + one atomic per wave (segment base order is
// run-varying but per-node contents identical — same class as hist atomics) ----
__global__ void offsets_kernel(const int* __restrict__ deg, int* __restrict__ off,
                               int* __restrict__ total, int N) {
    int lane = threadIdx.x & 63;
    int gid = blockIdx.x * blockDim.x + threadIdx.x;
    int x = (gid < N) ? deg[gid] : 0;
    int incl = x;
    #pragma unroll
    for (int s = 1; s < 64; s <<= 1) {
        int y = __shfl_up(incl, s);
        if (lane >= s) incl += y;
    }
    int wtot = __shfl(incl, 63);
    int base = 0;
    if (lane == 63) base = atomicAdd(total, wtot);
    base = __shfl(base, 63);
    if (gid < N) off[gid] = base + incl - x;
}

// ---------------- scatter edge ids into CSR slots (4B random writes; eid is 6.4MB,
// L2-resident → write-allocate merges ~16 writes/line; do NOT bypass L2) ----
__global__ void scatter_eid_kernel(const int* __restrict__ dst,
                                   const unsigned short* __restrict__ idx,
                                   const int* __restrict__ off, int* __restrict__ eid, int E) {
    int e = blockIdx.x * blockDim.x + threadIdx.x;
    if (e >= E) return;
    eid[off[dst[e]] + (int)idx[e]] = e;
}

// ---------------- node reduce: 16 lanes/node, gather half4 payload via eid ----
__global__ void node_reduce_kernel(const uint2* __restrict__ pay,
                                   const int* __restrict__ eid,
                                   const int* __restrict__ off, const int* __restrict__ deg,
                                   const float* __restrict__ er,
                                   float* __restrict__ out, int N) {
    int lane = threadIdx.x & 63;
    int wave = (int)(((size_t)blockIdx.x * blockDim.x + threadIdx.x) >> 6);
    int g = lane >> 4;            // group 0..3 within wave
    int gl = lane & 15;           // lane within group
    int n = wave * 4 + g;
    if (n >= N) return;
    int o = off[n], dg = deg[n];
    float4 erv = *(const float4*)(er + (size_t)n * H);
    float n0 = 0.f, n1 = 0.f, n2 = 0.f, n3 = 0.f;
    float d0 = 0.f, d1 = 0.f, d2 = 0.f, d3 = 0.f;
    for (int i = gl; i < dg; i += 16) {
        uint2 w = pay[eid[o + i]];
        float2 f01 = __half22float2(*(const __half2*)&w.x);
        float2 f23 = __half22float2(*(const __half2*)&w.y);
        float e0 = f01.x + erv.x, e1 = f01.y + erv.y, e2 = f23.x + erv.z, e3 = f23.y + erv.w;
        e0 = e0 > 0.f ? e0 : NEG_SLOPE * e0;
        e1 = e1 > 0.f ? e1 : NEG_SLOPE * e1;
        e2 = e2 > 0.f ? e2 : NEG_SLOPE * e2;
        e3 = e3 > 0.f ? e3 : NEG_SLOPE * e3;
        float x0 = __expf(e0), x1 = __expf(e1), x2 = __expf(e2), x3 = __expf(e3);
        n0 += x0 * f01.x; n1 += x1 * f01.y; n2 += x2 * f23.x; n3 += x3 * f23.y;
        d0 += x0; d1 += x1; d2 += x2; d3 += x3;
    }
    #pragma unroll
    for (int s = 8; s; s >>= 1) {
        n0 += __shfl_down(n0, s, 16); n1 += __shfl_down(n1, s, 16);
        n2 += __shfl_down(n2, s, 16); n3 += __shfl_down(n3, s, 16);
        d0 += __shfl_down(d0, s, 16); d1 += __shfl_down(d1, s, 16);
        d2 += __shfl_down(d2, s, 16); d3 += __shfl_down(d3, s, 16);
    }
    if (gl == 0) {
        *(float4*)(out + (size_t)n * H) =
            make_float4(d0 > 0.f ? n0 / d0 : 0.f, d1 > 0.f ? n1 / d1 : 0.f,
                        d2 > 0.f ? n2 / d2 : 0.f, d3 > 0.f ? n3 / d3 : 0.f);
    }
}

// ---------------- fallback (small ws): fused atomic path ----
__global__ void node_proj_fb_kernel(const float* __restrict__ nfeat,
                                    const float* __restrict__ Wl, const float* __restrict__ Wr,
                                    const float* __restrict__ bv,
                                    float* __restrict__ el, float* __restrict__ er,
                                    float* __restrict__ num, float* __restrict__ den, int N) {
    __shared__ float sWl[NODE_F * H];
    __shared__ float sWr[NODE_F * H];
    for (int i = threadIdx.x; i < NODE_F * H; i += blockDim.x) { sWl[i] = Wl[i]; sWr[i] = Wr[i]; }
    __syncthreads();
    int n = blockIdx.x * blockDim.x + threadIdx.x;
    if (n >= N) return;
    float accl[H] = {0.f, 0.f, 0.f, 0.f};
    float accr[H] = {0.f, 0.f, 0.f, 0.f};
    const float4* row = (const float4*)(nfeat + (size_t)n * NODE_F);
    #pragma unroll
    for (int j = 0; j < NODE_F / 4; ++j) {
        float4 v = row[j];
        #pragma unroll
        for (int h = 0; h < H; ++h) {
            accl[h] += v.x * sWl[(4 * j + 0) * H + h] + v.y * sWl[(4 * j + 1) * H + h]
                     + v.z * sWl[(4 * j + 2) * H + h] + v.w * sWl[(4 * j + 3) * H + h];
            accr[h] += v.x * sWr[(4 * j + 0) * H + h] + v.y * sWr[(4 * j + 1) * H + h]
                     + v.z * sWr[(4 * j + 2) * H + h] + v.w * sWr[(4 * j + 3) * H + h];
        }
    }
    size_t base = (size_t)n * H;
    #pragma unroll
    for (int h = 0; h < H; ++h) {
        el[base + h] = accl[h] + bv[h];
        er[base + h] = accr[h] + bv[H + h];
        num[base + h] = 0.f;
        den[base + h] = 0.f;
    }
}

__global__ void edge_atomic_kernel(const float* __restrict__ efeat,
                                   const int* __restrict__ src, const int* __restrict__ dst,
                                   const float* __restrict__ We, const float* __restrict__ bv,
                                   const float* __restrict__ el, const float* __restrict__ er,
                                   float* __restrict__ num, float* __restrict__ den, int E) {
    __shared__ float sWe[EDGE_F * H];
    __shared__ float sbe[H];
    for (int i = threadIdx.x; i < EDGE_F * H; i += blockDim.x) sWe[i] = We[i];
    if (threadIdx.x < H) sbe[threadIdx.x] = bv[2 * H + threadIdx.x];
    __syncthreads();
    int e = blockIdx.x * blockDim.x + threadIdx.x;
    if (e >= E) return;
    float acc[H] = {sbe[0], sbe[1], sbe[2], sbe[3]};
    const float4* row = (const float4*)(efeat + (size_t)e * EDGE_F);
    #pragma unroll
    for (int j = 0; j < EDGE_F / 4; ++j) {
        float4 v = row[j];
        #pragma unroll
        for (int h = 0; h < H; ++h) {
            acc[h] += v.x * sWe[(4 * j + 0) * H + h] + v.y * sWe[(4 * j + 1) * H + h]
                    + v.z * sWe[(4 * j + 2) * H + h] + v.w * sWe[(4 * j + 3) * H + h];
        }
    }
    int s = src[e], d = dst[e];
    float4 elv = *(const float4*)(el + (size_t)s * H);
    float4 erv = *(const float4*)(er + (size_t)d * H);
    float p0 = elv.x + acc[0], p1 = elv.y + acc[1], p2 = elv.z + acc[2], p3 = elv.w + acc[3];
    float e0 = p0 + erv.x, e1 = p1 + erv.y, e2 = p2 + erv.z, e3 = p3 + erv.w;
    e0 = e0 > 0.f ? e0 : NEG_SLOPE * e0;
    e1 = e1 > 0.f ? e1 : NEG_SLOPE * e1;
    e2 = e2 > 0.f ? e2 : NEG_SLOPE * e2;
    e3 = e3 > 0.f ? e3 : NEG_SLOPE * e3;
    float x0 = __expf(e0), x1 = __expf(e1), x2 = __expf(e2), x3 = __expf(e3);
    float* nb = num + (size_t)d * H;
    float* db = den + (size_t)d * H;
    atomicAdd(nb + 0, x0 * p0); atomicAdd(nb + 1, x1 * p1);
    atomicAdd(nb + 2, x2 * p2); atomicAdd(nb + 3, x3 * p3);
    atomicAdd(db + 0, x0); atomicAdd(db + 1, x1);
    atomicAdd(db + 2, x2); atomicAdd(db + 3, x3);
}

__global__ void finalize_kernel(const float* __restrict__ num, const float* __restrict__ den,
                                float* __restrict__ out, int NH) {
    int i = blockIdx.x * blockDim.x + threadIdx.x;
    if (i < NH) {
        float d = den[i];
        out[i] = d > 0.f ? num[i] / d : 0.f;
    }
}

extern "C" void kernel_launch(void* const* d_in, const int* in_sizes, int n_in,
                              void* d_out, int out_size, void* d_ws, size_t ws_size,
                              hipStream_t stream) {
    const float* nfeat = (const float*)d_in[0];
    const float* efeat = (const float*)d_in[1];
    const float* Wn    = (const float*)d_in[2];
    const float* bn    = (const float*)d_in[3];
    const float* Wed   = (const float*)d_in[4];
    const float* bed   = (const float*)d_in[5];
    const float* al    = (const float*)d_in[6];
    const float* ar    = (const float*)d_in[7];
    const float* ae    = (const float*)d_in[8];
    const int*   src   = (const int*)d_in[9];
    const int*   dst   = (const int*)d_in[10];

    int N = in_sizes[0] / NODE_F;
    int E = in_sizes[1] / EDGE_F;
    float* out = (float*)d_out;
    float* ws  = (float*)d_ws;

    // CSR layout (float-element offsets; all 16B aligned)
    size_t p_pay  = 0;                       // E uint2 (half4 per edge, edge order)
    size_t p_el   = p_pay + (size_t)E * 2;
    size_t p_er   = p_el + (size_t)N * H;
    size_t p_Wl   = p_er + (size_t)N * H;
    size_t p_Wr   = p_Wl + 512;
    size_t p_We   = p_Wr + 512;
    size_t p_bv   = p_We + 256;
    size_t p_tot  = p_bv + 16;               // 1 int (+pad)
    size_t p_deg  = p_tot + 16;              // N ints
    size_t p_off  = p_deg + (size_t)N;       // N ints
    size_t p_idx  = p_off + (size_t)N;       // E u16 -> E/2 floats (+pad)
    size_t p_eid  = p_idx + ((size_t)E / 2 + 8);  // E ints
    size_t csr_total = (p_eid + (size_t)E) * sizeof(float);

    if (ws_size >= csr_total) {
        uint2* pay = (uint2*)(ws + p_pay);
        float* el  = ws + p_el;
        float* er  = ws + p_er;
        float* Wl  = ws + p_Wl;
        float* Wr  = ws + p_Wr;
        float* We  = ws + p_We;
        float* bv  = ws + p_bv;
        int* total = (int*)(ws + p_tot);
        int* deg   = (int*)(ws + p_deg);
        int* off   = (int*)(ws + p_off);
        unsigned short* idx = (unsigned short*)(ws + p_idx);
        int* eid   = (int*)(ws + p_eid);

        fold_kernel<<<1, 512, 0, stream>>>(Wn, bn, Wed, bed, al, ar, ae, Wl, Wr, We, bv, total);
        node_proj_kernel<<<(int)(((size_t)N * 4 + 255) / 256), 256, 0, stream>>>(
            nfeat, Wl, Wr, bv, el, er, deg, N);
        edge_proj_kernel<<<(int)(((size_t)E * 4 + 255) / 256), 256, 0, stream>>>(
            efeat, src, dst, We, bv, el, pay, idx, deg, E);
        offsets_kernel<<<(N + 255) / 256, 256, 0, stream>>>(deg, off, total, N);
        scatter_eid_kernel<<<(E + 255) / 256, 256, 0, stream>>>(dst, idx, off, eid, E);
        node_reduce_kernel<<<(int)(((size_t)N * 16 + 255) / 256), 256, 0, stream>>>(
            pay, eid, off, deg, er, out, N);
    } else {
        // atomic fallback layout
        float* el  = ws;
        float* er  = el + (size_t)N * H;
        float* num = er + (size_t)N * H;
        float* den = num + (size_t)N * H;
        float* Wl  = den + (size_t)N * H;
        float* Wr  = Wl + 512;
        float* We  = Wr + 512;
        float* bv  = We + 256;
        int* total = (int*)(bv + 16);

        fold_kernel<<<1, 512, 0, stream>>>(Wn, bn, Wed, bed, al, ar, ae, Wl, Wr, We, bv, total);
        node_proj_fb_kernel<<<(N + 255) / 256, 256, 0, stream>>>(nfeat, Wl, Wr, bv,
                                                                 el, er, num, den, N);
        edge_atomic_kernel<<<(E + 255) / 256, 256, 0, stream>>>(efeat, src, dst, We, bv,
                                                                el, er, num, den, E);
        finalize_kernel<<<(N * H + 255) / 256, 256, 0, stream>>>(num, den, out, N * H);
    }
}